// Round 1
// baseline (631.987 us; speedup 1.0000x reference)
//
#include <hip/hip_runtime.h>
#include <cstdint>

// One thread per 32-bit element group.
// Layout: element e owns floats [e*32 .. e*32+31], bit index j maps to IEEE bit (31-j).
// Each thread reads/writes a contiguous 128B run via float4; a wave's 8 successive
// float4 loads cover a contiguous 8KB region -> streaming-friendly.
__global__ __launch_bounds__(256) void spikefp32mul_kernel(
    const float* __restrict__ A, const float* __restrict__ B,
    float* __restrict__ O, int n_elems)
{
    int e = blockIdx.x * blockDim.x + threadIdx.x;
    if (e >= n_elems) return;

    const float4* a4 = reinterpret_cast<const float4*>(A) + (size_t)e * 8;
    const float4* b4 = reinterpret_cast<const float4*>(B) + (size_t)e * 8;

    uint32_t wa = 0u, wb = 0u;
#pragma unroll
    for (int i = 0; i < 8; ++i) {
        float4 a = a4[i];
        float4 b = b4[i];
        const int s = 31 - i * 4;   // shift for lane .x of this quad
        wa |= (a.x > 0.5f ? (1u << s)       : 0u)
            | (a.y > 0.5f ? (1u << (s - 1)) : 0u)
            | (a.z > 0.5f ? (1u << (s - 2)) : 0u)
            | (a.w > 0.5f ? (1u << (s - 3)) : 0u);
        wb |= (b.x > 0.5f ? (1u << s)       : 0u)
            | (b.y > 0.5f ? (1u << (s - 1)) : 0u)
            | (b.z > 0.5f ? (1u << (s - 2)) : 0u)
            | (b.w > 0.5f ? (1u << (s - 3)) : 0u);
    }

    float p = __uint_as_float(wa) * __uint_as_float(wb);  // IEEE fp32 mul, RNE
    uint32_t wp = __float_as_uint(p);

    float4* o4 = reinterpret_cast<float4*>(O) + (size_t)e * 8;
#pragma unroll
    for (int i = 0; i < 8; ++i) {
        const int s = 31 - i * 4;
        float4 o;
        o.x = (float)((wp >> s)       & 1u);
        o.y = (float)((wp >> (s - 1)) & 1u);
        o.z = (float)((wp >> (s - 2)) & 1u);
        o.w = (float)((wp >> (s - 3)) & 1u);
        o4[i] = o;
    }
}

extern "C" void kernel_launch(void* const* d_in, const int* in_sizes, int n_in,
                              void* d_out, int out_size, void* d_ws, size_t ws_size,
                              hipStream_t stream) {
    const float* A = (const float*)d_in[0];
    const float* B = (const float*)d_in[1];
    float* O = (float*)d_out;

    int n_elems = in_sizes[0] / 32;   // 2048*1024 = 2,097,152
    const int block = 256;
    const int grid = (n_elems + block - 1) / block;
    spikefp32mul_kernel<<<grid, block, 0, stream>>>(A, B, O, n_elems);
}

// Round 2
// 564.928 us; speedup vs baseline: 1.1187x; 1.1187x over previous
//
#include <hip/hip_runtime.h>
#include <cstdint>

// Fully coalesced scheme: lane i loads float4 #i (16B, consecutive across lanes).
// One element's 32 spike floats span 8 consecutive lanes (4 floats/lane).
// Each lane packs its 4 bits, pre-shifted into bit-reversed (IEEE MSB-first)
// position; a 3-step OR-butterfly (__shfl_xor 1,2,4 — within the aligned 8-lane
// group) gives every lane the full 32-bit word. All 8 lanes redundantly do the
// IEEE fp32 multiply, then each lane unpacks its own 4 output bits -> coalesced
// float4 store.
__global__ __launch_bounds__(256) void spikefp32mul_kernel(
    const float4* __restrict__ A4, const float4* __restrict__ B4,
    float4* __restrict__ O4, int n4)
{
    int g = blockIdx.x * blockDim.x + threadIdx.x;
    if (g >= n4) return;

    float4 a = A4[g];
    float4 b = B4[g];

    // float index f = 4g + c belongs to element g/8, bit j = f%32 = 4*(g&7)+c,
    // which is IEEE bit 31-j. Nibble base shift:
    const int sb = 28 - 4 * (g & 7);

    uint32_t wa = ((a.x > 0.5f ? 8u : 0u) | (a.y > 0.5f ? 4u : 0u) |
                   (a.z > 0.5f ? 2u : 0u) | (a.w > 0.5f ? 1u : 0u)) << sb;
    uint32_t wb = ((b.x > 0.5f ? 8u : 0u) | (b.y > 0.5f ? 4u : 0u) |
                   (b.z > 0.5f ? 2u : 0u) | (b.w > 0.5f ? 1u : 0u)) << sb;

    // OR-butterfly across the 8 lanes of this element group.
    wa |= (uint32_t)__shfl_xor((int)wa, 1, 64);
    wb |= (uint32_t)__shfl_xor((int)wb, 1, 64);
    wa |= (uint32_t)__shfl_xor((int)wa, 2, 64);
    wb |= (uint32_t)__shfl_xor((int)wb, 2, 64);
    wa |= (uint32_t)__shfl_xor((int)wa, 4, 64);
    wb |= (uint32_t)__shfl_xor((int)wb, 4, 64);

    float p = __uint_as_float(wa) * __uint_as_float(wb);  // IEEE fp32 mul, RNE
    uint32_t wp = __float_as_uint(p);

    float4 o;
    o.x = (float)((wp >> (sb + 3)) & 1u);
    o.y = (float)((wp >> (sb + 2)) & 1u);
    o.z = (float)((wp >> (sb + 1)) & 1u);
    o.w = (float)((wp >> sb) & 1u);
    O4[g] = o;
}

extern "C" void kernel_launch(void* const* d_in, const int* in_sizes, int n_in,
                              void* d_out, int out_size, void* d_ws, size_t ws_size,
                              hipStream_t stream) {
    const float4* A4 = (const float4*)d_in[0];
    const float4* B4 = (const float4*)d_in[1];
    float4* O4 = (float4*)d_out;

    int n4 = in_sizes[0] / 4;   // 16,777,216 float4s; 65536 blocks of 256
    const int block = 256;
    const int grid = (n4 + block - 1) / block;
    spikefp32mul_kernel<<<grid, block, 0, stream>>>(A4, B4, O4, n4);
}